// Round 5
// baseline (97.676 us; speedup 1.0000x reference)
//
#include <hip/hip_runtime.h>
#include <stdint.h>

// GINConv1d: B=4, N=8192, K=16, C_IN=C_OUT=128
//
// R4 post-mortem: kernel budget ~25.4 us (cvt ~5 + fused ~20); fused is
// latency-bound (R1: VALUBusy 6.5%, occ 29%, 13% HBM) with an L2-BW floor of
// ~5 us. R2's MB=16 regression was confounded by per-block fp32 W conversion
// (now preconverted). R5: retest high occupancy cleanly:
//  - MB=16, one thread per (row, 8ch): 16 x short8 gather loads = 64 data VGPRs,
//    peak ~110 VGPR -> fits launch_bounds(256,4) cap 128 -> 4 blocks/CU (50% occ).
//  - sched_barrier(0) pins all 16 loads before accumulation (R1: compiler
//    otherwise collapses to ~4-deep load-add chain).
//  - W pre-converted to bf16 (8 x 16B loads/thread, no VALU prologue).
//  - nt stores for out / nt loads for eidx: protect the 2 MiB/XCD gather set.
#define BATCH   4
#define NNODE   8192
#define KNBR    16
#define CIN     128
#define COUT    128
#define MB      16          // rows (nodes) per block -> 2048 blocks
#define THREADS 256
#define HS_STRIDE 136       // shorts per h_s row: 128 + 8 pad

#define XELEM   (BATCH * NNODE * CIN)          // 4194304 fp32 elements
#define WELEM   (COUT * CIN)                   // 16384 fp32 elements
#define CVT_XBLK (XELEM / (256 * 8))           // 2048 blocks for x
#define CVT_WBLK (WELEM / (256 * 8))           // 8 blocks for W

typedef __attribute__((ext_vector_type(8))) short short8;   // 8 bf16 (MFMA A/B frag)
typedef __attribute__((ext_vector_type(4))) float f32x4;
typedef __attribute__((ext_vector_type(4))) int   i32x4;    // native vec: ok for nontemporal builtins

__device__ __forceinline__ short bf16_rne(float f) {
    union { float f; uint32_t u; } v; v.f = f;
    return (short)((v.u + 0x7FFFu + ((v.u >> 16) & 1u)) >> 16);  // round-to-nearest-even
}
__device__ __forceinline__ float bf16_f32(short s) {
    union { uint32_t u; float f; } v; v.u = ((uint32_t)(uint16_t)s) << 16;
    return v.f;
}

// ---------------- prepass: {x, W} fp32 -> bf16 in workspace ------------------------
// blocks [0, 2048): x -> xb ;  blocks [2048, 2056): W -> wb (= xb + XELEM)
__global__ __launch_bounds__(256)
void cvt_bf16(const float* __restrict__ x, const float* __restrict__ W,
              ushort* __restrict__ xb) {
    const int bi = blockIdx.x;
    const float* src;
    ushort*      dst;
    int          gid;
    if (bi < CVT_XBLK) { src = x; dst = xb;          gid = bi * 256 + threadIdx.x; }
    else               { src = W; dst = xb + XELEM;  gid = (bi - CVT_XBLK) * 256 + threadIdx.x; }
    const f32x4* xp = (const f32x4*)src + (size_t)gid * 2;
    f32x4 a = __builtin_nontemporal_load(xp);        // fp32 source is dead after this
    f32x4 c = __builtin_nontemporal_load(xp + 1);
    short8 s;
    s[0]=bf16_rne(a[0]); s[1]=bf16_rne(a[1]); s[2]=bf16_rne(a[2]); s[3]=bf16_rne(a[3]);
    s[4]=bf16_rne(c[0]); s[5]=bf16_rne(c[1]); s[6]=bf16_rne(c[2]); s[7]=bf16_rne(c[3]);
    ((short8*)dst)[gid] = s;
}

// ---------------- fused gather + eps-residual + MFMA GEMM + bias + ReLU ------------
// launch_bounds(256,4): VGPR cap 128; peak use ~110 (16 js + 64 gather data +
// acc + addr) -> 4 blocks/CU resident = 16 waves/CU for latency hiding.
template<bool USEBF>
__global__ __launch_bounds__(THREADS, 4)
void gin_fused(const float*  __restrict__ x,      // [B,N,CIN] fp32
               const ushort* __restrict__ xb,     // [B,N,CIN] bf16 (if USEBF)
               const ushort* __restrict__ wb,     // [COUT,CIN] bf16 (if USEBF)
               const int*    __restrict__ eidx,   // [2,B,N,K] int32; plane 0 = source idx
               const float*  __restrict__ W,      // [COUT,CIN] fp32
               const float*  __restrict__ bias,   // [COUT] fp32
               const float*  __restrict__ epsp,   // [1] fp32
               float*        __restrict__ out)    // [B,N,COUT] fp32
{
    __shared__ __align__(16) short h_s[MB * HS_STRIDE];

    const int tid = threadIdx.x;
    // XCD-locality swizzle: blockIdx -> XCD round-robin (i & 7). Pin batch b to
    // XCDs {2b,2b+1} so each XCD's gather set = one batch (2 MiB bf16) -> L2-resident.
    const int i   = blockIdx.x;            // 0..2047
    const int xcd = i & 7;
    const int sub = i >> 3;                // 0..255
    const int b   = xcd >> 1;              // batch 0..3
    const int wbi = ((xcd & 1) << 8) | sub;// 0..511 within batch
    const int n0  = wbi * MB;
    const int row0 = b * NNODE + n0;

    const float eps1 = 1.0f + epsp[0];

    // ---------------- Phase A: gather + sum -> h_s (bf16) --------------------------
    {
        const int r  = tid >> 4;           // row within block, 0..15
        const int q  = tid & 15;           // channel slice, 8 ch each
        const int n  = n0 + r;
        const int c0 = q * 8;
        const int* ip = eidx + ((size_t)b * NNODE + n) * KNBR;   // plane 0

        int js[KNBR];
        #pragma unroll
        for (int p = 0; p < 4; ++p) {
            i32x4 jv = __builtin_nontemporal_load((const i32x4*)(ip + p * 4));
            js[p*4+0]=jv.x; js[p*4+1]=jv.y; js[p*4+2]=jv.z; js[p*4+3]=jv.w;
        }

        float acc[8];

        if constexpr (USEBF) {
            const ushort* xbb = xb + (size_t)b * NNODE * CIN;
            short8 s0 = *(const short8*)(xbb + (size_t)n * CIN + c0);

            // ALL 16 neighbor slices prefetched (16 x 16B loads in flight per
            // thread); sched_barrier(0) pins the loads before any accumulation.
            short8 t[KNBR];
            #pragma unroll
            for (int k = 0; k < KNBR; ++k)
                t[k] = *(const short8*)(xbb + (size_t)js[k] * CIN + c0);
            __builtin_amdgcn_sched_barrier(0);

            #pragma unroll
            for (int e = 0; e < 8; ++e) acc[e] = eps1 * bf16_f32(s0[e]);
            #pragma unroll
            for (int k = 0; k < KNBR; ++k) {
                #pragma unroll
                for (int e = 0; e < 8; ++e) acc[e] += bf16_f32(t[k][e]);
            }
        } else {
            const float* xbb = x + (size_t)b * NNODE * CIN;
            const float* xs  = xbb + (size_t)n * CIN + c0;
            f32x4 v0 = *(const f32x4*)(xs);
            f32x4 v1 = *(const f32x4*)(xs + 4);
            #pragma unroll
            for (int e = 0; e < 4; ++e) { acc[e] = eps1*v0[e]; acc[4+e] = eps1*v1[e]; }
            #pragma unroll
            for (int k = 0; k < KNBR; ++k) {
                const float* xn = xbb + (size_t)js[k] * CIN + c0;
                f32x4 w0 = *(const f32x4*)(xn);
                f32x4 w1 = *(const f32x4*)(xn + 4);
                #pragma unroll
                for (int e = 0; e < 4; ++e) { acc[e] += w0[e]; acc[4+e] += w1[e]; }
            }
        }

        short* hp = h_s + r * HS_STRIDE + c0;
        short8 s;
        #pragma unroll
        for (int e = 0; e < 8; ++e) s[e] = bf16_rne(acc[e]);
        *(short8*)hp = s;
    }

    // ---------------- W -> bf16 B-fragments (after gather: caps peak VGPR) ---------
    const int wave = tid >> 6;
    const int lane = tid & 63;
    const int l16  = lane & 15;
    const int lq   = lane >> 4;            // quad 0..3

    short8 bfrag[2][4];                    // [o_tile][kb]: B[k][n]=W[o][c], n=l16, k=lq*8+j
    if constexpr (USEBF) {
        #pragma unroll
        for (int t = 0; t < 2; ++t) {
            const ushort* wp = wb + (size_t)(wave * 32 + t * 16 + l16) * CIN;
            #pragma unroll
            for (int kb = 0; kb < 4; ++kb)
                bfrag[t][kb] = *(const short8*)(wp + kb * 32 + lq * 8);
        }
    } else {
        #pragma unroll
        for (int t = 0; t < 2; ++t) {
            const float* wp = W + (size_t)(wave * 32 + t * 16 + l16) * CIN;
            #pragma unroll
            for (int kb = 0; kb < 4; ++kb) {
                const float* wq = wp + kb * 32 + lq * 8;
                f32x4 f0 = *(const f32x4*)(wq);
                f32x4 f1 = *(const f32x4*)(wq + 4);
                short8 s;
                s[0]=bf16_rne(f0[0]); s[1]=bf16_rne(f0[1]); s[2]=bf16_rne(f0[2]); s[3]=bf16_rne(f0[3]);
                s[4]=bf16_rne(f1[0]); s[5]=bf16_rne(f1[1]); s[6]=bf16_rne(f1[2]); s[7]=bf16_rne(f1[3]);
                bfrag[t][kb] = s;
            }
        }
    }
    const float bias0 = bias[wave * 32 + l16];
    const float bias1 = bias[wave * 32 + 16 + l16];

    __syncthreads();

    // ---------------- Phase B: MFMA GEMM + bias + ReLU -----------------------------
    float* outb = out + (size_t)row0 * COUT;
    {
        const short* ap = h_s + l16 * HS_STRIDE + lq * 8;
        short8 afrag[4];
        #pragma unroll
        for (int kb = 0; kb < 4; ++kb)
            afrag[kb] = *(const short8*)(ap + kb * 32);

        #pragma unroll
        for (int t = 0; t < 2; ++t) {
            f32x4 acc = { 0.f, 0.f, 0.f, 0.f };
            #pragma unroll
            for (int kb = 0; kb < 4; ++kb)
                acc = __builtin_amdgcn_mfma_f32_16x16x32_bf16(afrag[kb], bfrag[t][kb], acc, 0, 0, 0);

            const float bv  = t ? bias1 : bias0;
            const int   col = wave * 32 + t * 16 + l16;
            #pragma unroll
            for (int ii = 0; ii < 4; ++ii) {
                const int row = lq * 4 + ii;             // C/D: row = quad*4 + reg
                float v = acc[ii] + bv;
                v = v > 0.f ? v : 0.f;
                // nt store: the 16 MiB out stream must not evict the bf16 gather set
                __builtin_nontemporal_store(v, &outb[(size_t)row * COUT + col]);
            }
        }
    }
}

extern "C" void kernel_launch(void* const* d_in, const int* in_sizes, int n_in,
                              void* d_out, int out_size, void* d_ws, size_t ws_size,
                              hipStream_t stream) {
    const float* x    = (const float*)d_in[0];
    const int*   eidx = (const int*)d_in[1];
    const float* W    = (const float*)d_in[2];
    const float* bias = (const float*)d_in[3];
    const float* eps  = (const float*)d_in[4];
    float*       out  = (float*)d_out;

    const size_t need = (size_t)(XELEM + WELEM) * sizeof(ushort);  // 8 MiB + 32 KiB
    dim3 grid((BATCH * NNODE) / MB);   // 2048 blocks

    if (ws_size >= need) {
        ushort* xb = (ushort*)d_ws;
        cvt_bf16<<<dim3(CVT_XBLK + CVT_WBLK), dim3(256), 0, stream>>>(x, W, xb);
        gin_fused<true><<<grid, dim3(THREADS), 0, stream>>>(x, xb, xb + XELEM, eidx, W, bias, eps, out);
    } else {
        gin_fused<false><<<grid, dim3(THREADS), 0, stream>>>(x, nullptr, nullptr, eidx, W, bias, eps, out);
    }
}